// Round 2
// baseline (277.830 us; speedup 1.0000x reference)
//
#include <hip/hip_runtime.h>
#include <hip/hip_bf16.h>
#include <math.h>

typedef __attribute__((ext_vector_type(8))) short bf16x8;
typedef __attribute__((ext_vector_type(4))) float f32x4;

// ---------------------------------------------------------------------------
// Kernel 1: x = LayerNorm(token_embedding + PE)  -> bf16 [4096,1024]
// one block per row (b*1024+t), 256 threads, 4 elems/thread (float4 load)
// ---------------------------------------------------------------------------
__global__ __launch_bounds__(256) void peln_kernel(
    const float* __restrict__ emb,
    const float* __restrict__ gamma,
    const float* __restrict__ beta,
    __hip_bfloat16* __restrict__ x)
{
    const int row = blockIdx.x;        // 0..4095
    const int t   = row & 1023;        // position within sequence
    const int tid = threadIdx.x;

    float4 e = ((const float4*)(emb + (size_t)row * 1024))[tid];
    float v[4] = {e.x, e.y, e.z, e.w};
    float s = 0.f, ss = 0.f;
    #pragma unroll
    for (int kk = 0; kk < 4; ++kk) {
        int c = tid * 4 + kk;
        // angle = t / 10000^((c&~1)/1024) = t * 2^(-log2(1e4) * (c>>1)/512)
        float ang = (float)t * exp2f(-13.287712379549449f * (float)(c >> 1) * (1.0f / 512.0f));
        float pe  = (c & 1) ? cosf(ang) : sinf(ang);
        v[kk] += pe;
        s  += v[kk];
        ss += v[kk] * v[kk];
    }
    #pragma unroll
    for (int off = 1; off < 64; off <<= 1) {
        s  += __shfl_xor(s, off);
        ss += __shfl_xor(ss, off);
    }
    __shared__ float red_s[4], red_ss[4];
    int wave = tid >> 6, lane = tid & 63;
    if (lane == 0) { red_s[wave] = s; red_ss[wave] = ss; }
    __syncthreads();
    float S  = red_s[0] + red_s[1] + red_s[2] + red_s[3];
    float SS = red_ss[0] + red_ss[1] + red_ss[2] + red_ss[3];
    float mu   = S * (1.0f / 1024.0f);
    float var  = SS * (1.0f / 1024.0f) - mu * mu;
    float rstd = rsqrtf(var + 1e-5f);
    #pragma unroll
    for (int kk = 0; kk < 4; ++kk) {
        int c = tid * 4 + kk;
        float y = (v[kk] - mu) * rstd * gamma[c] + beta[c];
        x[(size_t)row * 1024 + c] = __float2bfloat16(y);
    }
}

// ---------------------------------------------------------------------------
// Kernel 2: transpose+cast Wq/Wk/Wv (f32 1024x1024) -> bf16 Wt[3][1024][1024],
// Wt[t][n][k] = W[t][k][n]
// ---------------------------------------------------------------------------
__global__ void wt_kernel(const float* __restrict__ Wq,
                          const float* __restrict__ Wk,
                          const float* __restrict__ Wv,
                          __hip_bfloat16* __restrict__ Wt)
{
    __shared__ __hip_bfloat16 tile[32][33];
    int zz = blockIdx.z;
    const float* src = (zz == 0) ? Wq : (zz == 1) ? Wk : Wv;
    __hip_bfloat16* dst = Wt + (size_t)zz * 1024 * 1024;
    int x0 = blockIdx.x * 32, y0 = blockIdx.y * 32;
    int tx = threadIdx.x, ty = threadIdx.y;   // (32,8)
    #pragma unroll
    for (int kk = 0; kk < 4; ++kk)
        tile[ty + 8 * kk][tx] =
            __float2bfloat16(src[(size_t)(y0 + ty + 8 * kk) * 1024 + x0 + tx]);
    __syncthreads();
    #pragma unroll
    for (int kk = 0; kk < 4; ++kk)
        dst[(size_t)(x0 + ty + 8 * kk) * 1024 + y0 + tx] = tile[tx][ty + 8 * kk];
}

// ---------------------------------------------------------------------------
// Kernel 3: fused QKV GEMM  qkv[t] = x @ W[t] + b[t], bf16 MFMA 16x16x32
// block = 256 thr (4 waves), block tile 64(M) x 256(N); wave tile 64x64 (4x4)
// ---------------------------------------------------------------------------
__global__ __launch_bounds__(256) void qkv_gemm(
    const __hip_bfloat16* __restrict__ X,    // [4096,1024] bf16
    const __hip_bfloat16* __restrict__ Wt,   // [3][1024][1024] bf16 N-major
    const float* __restrict__ bq,
    const float* __restrict__ bk,
    const float* __restrict__ bv,
    __hip_bfloat16* __restrict__ qkv)        // [3][4096][1024] bf16
{
    const int m0   = blockIdx.x * 64;
    const int gn0  = blockIdx.y * 256;
    const int wave = threadIdx.x >> 6, lane = threadIdx.x & 63;
    const int n0g  = gn0 + wave * 64;
    const int t    = n0g >> 10;
    const int nn0  = n0g & 1023;
    const __hip_bfloat16* W = Wt + (size_t)t * 1024 * 1024;
    const int lm = lane & 15, quad = lane >> 4;

    f32x4 acc[4][4];
    #pragma unroll
    for (int i = 0; i < 4; ++i)
        #pragma unroll
        for (int j = 0; j < 4; ++j)
            acc[i][j] = (f32x4){0.f, 0.f, 0.f, 0.f};

    for (int k0 = 0; k0 < 1024; k0 += 32) {
        bf16x8 a[4], b[4];
        #pragma unroll
        for (int i = 0; i < 4; ++i)
            a[i] = *(const bf16x8*)(X + (size_t)(m0 + 16 * i + lm) * 1024 + k0 + quad * 8);
        #pragma unroll
        for (int j = 0; j < 4; ++j)
            b[j] = *(const bf16x8*)(W + (size_t)(nn0 + 16 * j + lm) * 1024 + k0 + quad * 8);
        #pragma unroll
        for (int i = 0; i < 4; ++i)
            #pragma unroll
            for (int j = 0; j < 4; ++j)
                acc[i][j] = __builtin_amdgcn_mfma_f32_16x16x32_bf16(a[i], b[j], acc[i][j], 0, 0, 0);
    }

    const float* bias = (t == 0) ? bq : (t == 1) ? bk : bv;
    __hip_bfloat16* out = qkv + (size_t)t * 4096 * 1024;
    #pragma unroll
    for (int j = 0; j < 4; ++j) {
        float bb = bias[nn0 + 16 * j + lm];
        #pragma unroll
        for (int i = 0; i < 4; ++i) {
            #pragma unroll
            for (int r = 0; r < 4; ++r) {
                int row = m0 + 16 * i + quad * 4 + r;
                int col = nn0 + 16 * j + lm;
                out[(size_t)row * 1024 + col] = __float2bfloat16(acc[i][j][r] + bb);
            }
        }
    }
}

// ---------------------------------------------------------------------------
// Kernel 4: vt[bh][d][n] = v[(b*1024+n)*1024 + h*64 + d]   (V^T per head)
// ---------------------------------------------------------------------------
__global__ void vt_kernel(const __hip_bfloat16* __restrict__ v,
                          __hip_bfloat16* __restrict__ vt)
{
    __shared__ __hip_bfloat16 tile[32][33];
    int bh = blockIdx.z;
    int b = bh >> 4, h = bh & 15;
    int n0 = blockIdx.x * 32, d0 = blockIdx.y * 32;
    int tx = threadIdx.x, ty = threadIdx.y;  // (32,8)
    #pragma unroll
    for (int kk = 0; kk < 4; ++kk)
        tile[ty + 8 * kk][tx] =
            v[(size_t)(b * 1024 + n0 + ty + 8 * kk) * 1024 + h * 64 + d0 + tx];
    __syncthreads();
    #pragma unroll
    for (int kk = 0; kk < 4; ++kk)
        vt[((size_t)bh * 64 + d0 + ty + 8 * kk) * 1024 + n0 + tx] = tile[tx][ty + 8 * kk];
}

// ---------------------------------------------------------------------------
// Kernel 5: flash attention. block=256 (4 waves); block: one (b,h), 128 Q rows;
// wave: 32 Q rows. K-tiles of 32, online softmax, P via LDS C->A layout.
// ---------------------------------------------------------------------------
__global__ __launch_bounds__(256) void attn_kernel(
    const __hip_bfloat16* __restrict__ q,    // [4096,1024]
    const __hip_bfloat16* __restrict__ k,    // [4096,1024]
    const __hip_bfloat16* __restrict__ vt,   // [64][64][1024]
    float* __restrict__ out)                 // [4096,1024] f32
{
    __shared__ __align__(16) __hip_bfloat16 lds_p[4][32][40];
    const int qblk = blockIdx.x;   // 0..7
    const int bh   = blockIdx.y;   // 0..63
    const int b = bh >> 4, h = bh & 15;
    const int wave = threadIdx.x >> 6, lane = threadIdx.x & 63;
    const int lm = lane & 15, quad = lane >> 4;
    const int qbase = qblk * 128 + wave * 32;

    bf16x8 aq[2][2];
    #pragma unroll
    for (int i = 0; i < 2; ++i)
        #pragma unroll
        for (int ks = 0; ks < 2; ++ks)
            aq[i][ks] = *(const bf16x8*)(q + (size_t)(b * 1024 + qbase + 16 * i + lm) * 1024
                                           + h * 64 + ks * 32 + quad * 8);

    f32x4 O[2][4];
    float mi[2][4], li[2][4];
    #pragma unroll
    for (int i = 0; i < 2; ++i) {
        #pragma unroll
        for (int nt = 0; nt < 4; ++nt) O[i][nt] = (f32x4){0.f, 0.f, 0.f, 0.f};
        #pragma unroll
        for (int r = 0; r < 4; ++r) { mi[i][r] = -1e30f; li[i][r] = 0.f; }
    }

    for (int kt = 0; kt < 1024; kt += 32) {
        bf16x8 bkf[2][2];
        #pragma unroll
        for (int jt = 0; jt < 2; ++jt)
            #pragma unroll
            for (int ks = 0; ks < 2; ++ks)
                bkf[jt][ks] = *(const bf16x8*)(k + (size_t)(b * 1024 + kt + 16 * jt + lm) * 1024
                                                 + h * 64 + ks * 32 + quad * 8);
        f32x4 S[2][2];
        #pragma unroll
        for (int i = 0; i < 2; ++i)
            #pragma unroll
            for (int jt = 0; jt < 2; ++jt) {
                S[i][jt] = (f32x4){0.f, 0.f, 0.f, 0.f};
                S[i][jt] = __builtin_amdgcn_mfma_f32_16x16x32_bf16(aq[i][0], bkf[jt][0], S[i][jt], 0, 0, 0);
                S[i][jt] = __builtin_amdgcn_mfma_f32_16x16x32_bf16(aq[i][1], bkf[jt][1], S[i][jt], 0, 0, 0);
            }

        #pragma unroll
        for (int i = 0; i < 2; ++i) {
            #pragma unroll
            for (int r = 0; r < 4; ++r) {
                float s0 = S[i][0][r] * 0.125f;
                float s1 = S[i][1][r] * 0.125f;
                float mx = fmaxf(s0, s1);
                #pragma unroll
                for (int off = 1; off < 16; off <<= 1) mx = fmaxf(mx, __shfl_xor(mx, off));
                float mnew  = fmaxf(mi[i][r], mx);
                float alpha = __expf(mi[i][r] - mnew);
                float p0 = __expf(s0 - mnew);
                float p1 = __expf(s1 - mnew);
                float rs = p0 + p1;
                #pragma unroll
                for (int off = 1; off < 16; off <<= 1) rs += __shfl_xor(rs, off);
                li[i][r] = li[i][r] * alpha + rs;
                mi[i][r] = mnew;
                #pragma unroll
                for (int nt = 0; nt < 4; ++nt) O[i][nt][r] *= alpha;
                int rl = 16 * i + quad * 4 + r;
                lds_p[wave][rl][lm]      = __float2bfloat16(p0);
                lds_p[wave][rl][16 + lm] = __float2bfloat16(p1);
            }
        }
        __syncthreads();   // order LDS P writes before A-layout reads

        bf16x8 ap[2], bvf[4];
        #pragma unroll
        for (int i = 0; i < 2; ++i)
            ap[i] = *(const bf16x8*)(&lds_p[wave][16 * i + lm][quad * 8]);
        #pragma unroll
        for (int nt = 0; nt < 4; ++nt)
            bvf[nt] = *(const bf16x8*)(vt + ((size_t)bh * 64 + 16 * nt + lm) * 1024 + kt + quad * 8);
        #pragma unroll
        for (int i = 0; i < 2; ++i)
            #pragma unroll
            for (int nt = 0; nt < 4; ++nt)
                O[i][nt] = __builtin_amdgcn_mfma_f32_16x16x32_bf16(ap[i], bvf[nt], O[i][nt], 0, 0, 0);
        __syncthreads();   // protect LDS against next-iteration overwrite
    }

    #pragma unroll
    for (int i = 0; i < 2; ++i) {
        #pragma unroll
        for (int nt = 0; nt < 4; ++nt) {
            #pragma unroll
            for (int r = 0; r < 4; ++r) {
                float o = O[i][nt][r] / li[i][r];
                int qrow = qbase + 16 * i + quad * 4 + r;
                out[(size_t)(b * 1024 + qrow) * 1024 + h * 64 + 16 * nt + lm] = o;
            }
        }
    }
}

// ---------------------------------------------------------------------------
extern "C" void kernel_launch(void* const* d_in, const int* in_sizes, int n_in,
                              void* d_out, int out_size, void* d_ws, size_t ws_size,
                              hipStream_t stream)
{
    const float* emb   = (const float*)d_in[0];
    const float* gamma = (const float*)d_in[1];
    const float* beta  = (const float*)d_in[2];
    const float* Wq    = (const float*)d_in[3];
    const float* bq    = (const float*)d_in[4];
    const float* Wk    = (const float*)d_in[5];
    const float* bk    = (const float*)d_in[6];
    const float* Wv    = (const float*)d_in[7];
    const float* bv    = (const float*)d_in[8];
    float* out = (float*)d_out;

    __hip_bfloat16* ws  = (__hip_bfloat16*)d_ws;
    __hip_bfloat16* x   = ws;                            //  4M elems bf16
    __hip_bfloat16* Wt  = x   + (size_t)4096 * 1024;     //  3M elems
    __hip_bfloat16* qkv = Wt  + (size_t)3 * 1024 * 1024; // 12M elems
    __hip_bfloat16* vt  = qkv + (size_t)3 * 4096 * 1024; //  4M elems (46MB total)

    peln_kernel<<<4096, 256, 0, stream>>>(emb, gamma, beta, x);
    wt_kernel<<<dim3(32, 32, 3), dim3(32, 8), 0, stream>>>(Wq, Wk, Wv, Wt);
    qkv_gemm<<<dim3(64, 12), 256, 0, stream>>>(x, Wt, bq, bk, bv, qkv);
    vt_kernel<<<dim3(32, 2, 64), dim3(32, 8), 0, stream>>>(qkv + (size_t)2 * 4096 * 1024, vt);
    attn_kernel<<<dim3(8, 64), 256, 0, stream>>>(qkv, qkv + (size_t)4096 * 1024, vt, out);
}

// Round 3
// 219.220 us; speedup vs baseline: 1.2674x; 1.2674x over previous
//
#include <hip/hip_runtime.h>
#include <hip/hip_bf16.h>
#include <math.h>

typedef __attribute__((ext_vector_type(8))) short bf16x8;
typedef __attribute__((ext_vector_type(4))) float f32x4;

// async global->LDS, 16B per lane. LDS dest = wave-uniform base + lane*16.
static __device__ __forceinline__ void gld16(const void* g, void* l) {
    __builtin_amdgcn_global_load_lds(
        (const __attribute__((address_space(1))) unsigned int*)g,
        (__attribute__((address_space(3))) unsigned int*)l, 16, 0, 0);
}

// ---------------------------------------------------------------------------
// Kernel 1: x = LayerNorm(token_embedding + PE)  -> bf16 [4096,1024]
// ---------------------------------------------------------------------------
__global__ __launch_bounds__(256) void peln_kernel(
    const float* __restrict__ emb,
    const float* __restrict__ gamma,
    const float* __restrict__ beta,
    __hip_bfloat16* __restrict__ x)
{
    const int row = blockIdx.x;        // 0..4095
    const int t   = row & 1023;        // position within sequence
    const int tid = threadIdx.x;

    float4 e = ((const float4*)(emb + (size_t)row * 1024))[tid];
    float v[4] = {e.x, e.y, e.z, e.w};
    float s = 0.f, ss = 0.f;
    #pragma unroll
    for (int kk = 0; kk < 4; ++kk) {
        int c = tid * 4 + kk;
        float ang = (float)t * exp2f(-13.287712379549449f * (float)(c >> 1) * (1.0f / 512.0f));
        float pe  = (c & 1) ? cosf(ang) : sinf(ang);
        v[kk] += pe;
        s  += v[kk];
        ss += v[kk] * v[kk];
    }
    #pragma unroll
    for (int off = 1; off < 64; off <<= 1) {
        s  += __shfl_xor(s, off);
        ss += __shfl_xor(ss, off);
    }
    __shared__ float red_s[4], red_ss[4];
    int wave = tid >> 6, lane = tid & 63;
    if (lane == 0) { red_s[wave] = s; red_ss[wave] = ss; }
    __syncthreads();
    float S  = red_s[0] + red_s[1] + red_s[2] + red_s[3];
    float SS = red_ss[0] + red_ss[1] + red_ss[2] + red_ss[3];
    float mu   = S * (1.0f / 1024.0f);
    float var  = SS * (1.0f / 1024.0f) - mu * mu;
    float rstd = rsqrtf(var + 1e-5f);
    #pragma unroll
    for (int kk = 0; kk < 4; ++kk) {
        int c = tid * 4 + kk;
        float y = (v[kk] - mu) * rstd * gamma[c] + beta[c];
        x[(size_t)row * 1024 + c] = __float2bfloat16(y);
    }
}

// ---------------------------------------------------------------------------
// Kernel 2: transpose+cast Wq/Wk/Wv (f32) -> bf16 Wt[3][1024][1024] (N-major)
// ---------------------------------------------------------------------------
__global__ void wt_kernel(const float* __restrict__ Wq,
                          const float* __restrict__ Wk,
                          const float* __restrict__ Wv,
                          __hip_bfloat16* __restrict__ Wt)
{
    __shared__ __hip_bfloat16 tile[32][33];
    int zz = blockIdx.z;
    const float* src = (zz == 0) ? Wq : (zz == 1) ? Wk : Wv;
    __hip_bfloat16* dst = Wt + (size_t)zz * 1024 * 1024;
    int x0 = blockIdx.x * 32, y0 = blockIdx.y * 32;
    int tx = threadIdx.x, ty = threadIdx.y;   // (32,8)
    #pragma unroll
    for (int kk = 0; kk < 4; ++kk)
        tile[ty + 8 * kk][tx] =
            __float2bfloat16(src[(size_t)(y0 + ty + 8 * kk) * 1024 + x0 + tx]);
    __syncthreads();
    #pragma unroll
    for (int kk = 0; kk < 4; ++kk)
        dst[(size_t)(x0 + ty + 8 * kk) * 1024 + y0 + tx] = tile[tx][ty + 8 * kk];
}

// ---------------------------------------------------------------------------
// Kernel 3: fused QKV GEMM, m97 structure: 128x128 tile, BK=32,
// global_load_lds width-16 staging, ds_read_b128 frags, MFMA after barrier 2.
// block = 256 thr (4 waves, 2x2), wave tile 64x64 (4x4 frags of 16x16x32)
// ---------------------------------------------------------------------------
__global__ __launch_bounds__(256) void qkv_gemm(
    const __hip_bfloat16* __restrict__ X,    // [4096,1024] bf16
    const __hip_bfloat16* __restrict__ Wt,   // [3][1024][1024] bf16 N-major
    const float* __restrict__ bq,
    const float* __restrict__ bk,
    const float* __restrict__ bv,
    __hip_bfloat16* __restrict__ qkv)        // [3][4096][1024] bf16
{
    __shared__ __align__(16) __hip_bfloat16 Abuf[128 * 32];  // 8 KB, [row][k]
    __shared__ __align__(16) __hip_bfloat16 Bbuf[128 * 32];  // 8 KB, [n][k]

    const int m0  = blockIdx.x * 128;
    const int n0  = blockIdx.y * 128;        // 0..2944; tile never straddles tensors
    const int t   = n0 >> 10;
    const int nn0 = n0 & 1023;
    const __hip_bfloat16* W = Wt + (size_t)t * 1024 * 1024;

    const int tid  = threadIdx.x;
    const int wave = tid >> 6, lane = tid & 63;
    const int wm = wave & 1, wn = wave >> 1;
    const int lm = lane & 15, quad = lane >> 4;

    // staging map: issue covers 64 rows; thread -> row = tid/4, kchunk = (tid%4)*8
    const int srow = tid >> 2;
    const int skc  = (tid & 3) * 8;
    const __hip_bfloat16* gA0 = X + (size_t)(m0 + srow) * 1024 + skc;
    const __hip_bfloat16* gA1 = X + (size_t)(m0 + 64 + srow) * 1024 + skc;
    const __hip_bfloat16* gB0 = W + (size_t)(nn0 + srow) * 1024 + skc;
    const __hip_bfloat16* gB1 = W + (size_t)(nn0 + 64 + srow) * 1024 + skc;
    __hip_bfloat16* lA0 = Abuf + wave * 512;          // wave-uniform LDS bases
    __hip_bfloat16* lA1 = Abuf + 2048 + wave * 512;
    __hip_bfloat16* lB0 = Bbuf + wave * 512;
    __hip_bfloat16* lB1 = Bbuf + 2048 + wave * 512;

    f32x4 acc[4][4];
    #pragma unroll
    for (int i = 0; i < 4; ++i)
        #pragma unroll
        for (int j = 0; j < 4; ++j)
            acc[i][j] = (f32x4){0.f, 0.f, 0.f, 0.f};

    for (int k0 = 0; k0 < 1024; k0 += 32) {
        gld16(gA0 + k0, lA0);
        gld16(gA1 + k0, lA1);
        gld16(gB0 + k0, lB0);
        gld16(gB1 + k0, lB1);
        __syncthreads();                      // drain staging (vmcnt) + barrier

        bf16x8 a[4], b[4];
        #pragma unroll
        for (int i = 0; i < 4; ++i)
            a[i] = *(const bf16x8*)(Abuf + (size_t)(wm * 64 + i * 16 + lm) * 32 + quad * 8);
        #pragma unroll
        for (int j = 0; j < 4; ++j)
            b[j] = *(const bf16x8*)(Bbuf + (size_t)(wn * 64 + j * 16 + lm) * 32 + quad * 8);
        __syncthreads();                      // frags in regs; LDS free for next iter

        #pragma unroll
        for (int i = 0; i < 4; ++i)
            #pragma unroll
            for (int j = 0; j < 4; ++j)
                acc[i][j] = __builtin_amdgcn_mfma_f32_16x16x32_bf16(a[i], b[j], acc[i][j], 0, 0, 0);
        // next iteration's gld16 co-schedules with these MFMAs (no barrier between)
    }

    const float* bias = (t == 0) ? bq : (t == 1) ? bk : bv;
    __hip_bfloat16* out = qkv + (size_t)t * 4096 * 1024;
    #pragma unroll
    for (int j = 0; j < 4; ++j) {
        int col = nn0 + wn * 64 + j * 16 + lm;
        float bb = bias[col];
        #pragma unroll
        for (int i = 0; i < 4; ++i) {
            #pragma unroll
            for (int r = 0; r < 4; ++r) {
                int row = m0 + wm * 64 + i * 16 + quad * 4 + r;
                out[(size_t)row * 1024 + col] = __float2bfloat16(acc[i][j][r] + bb);
            }
        }
    }
}

// ---------------------------------------------------------------------------
// Kernel 4: vt[bh][d][n] = v[(b*1024+n)*1024 + h*64 + d]   (V^T per head)
// ---------------------------------------------------------------------------
__global__ void vt_kernel(const __hip_bfloat16* __restrict__ v,
                          __hip_bfloat16* __restrict__ vt)
{
    __shared__ __hip_bfloat16 tile[32][33];
    int bh = blockIdx.z;
    int b = bh >> 4, h = bh & 15;
    int n0 = blockIdx.x * 32, d0 = blockIdx.y * 32;
    int tx = threadIdx.x, ty = threadIdx.y;  // (32,8)
    #pragma unroll
    for (int kk = 0; kk < 4; ++kk)
        tile[ty + 8 * kk][tx] =
            v[(size_t)(b * 1024 + n0 + ty + 8 * kk) * 1024 + h * 64 + d0 + tx];
    __syncthreads();
    #pragma unroll
    for (int kk = 0; kk < 4; ++kk)
        vt[((size_t)bh * 64 + d0 + ty + 8 * kk) * 1024 + n0 + tx] = tile[tx][ty + 8 * kk];
}

// ---------------------------------------------------------------------------
// Kernel 5: flash attention, XCD-swizzled 1-D grid (each XCD owns 8 bh pairs).
// ---------------------------------------------------------------------------
__global__ __launch_bounds__(256) void attn_kernel(
    const __hip_bfloat16* __restrict__ q,    // [4096,1024]
    const __hip_bfloat16* __restrict__ k,    // [4096,1024]
    const __hip_bfloat16* __restrict__ vt,   // [64][64][1024]
    float* __restrict__ out)                 // [4096,1024] f32
{
    __shared__ __align__(16) __hip_bfloat16 lds_p[4][32][40];
    // XCD swizzle: round-robin dispatch puts id%8 on XCD id%8; give each XCD
    // 8 contiguous bh (K/V set 2MB < 4MB L2)
    const int id   = blockIdx.x;             // 0..511
    const int bh   = (id & 7) * 8 + ((id >> 3) & 7);
    const int qblk = id >> 6;                // 0..7
    const int b = bh >> 4, h = bh & 15;
    const int wave = threadIdx.x >> 6, lane = threadIdx.x & 63;
    const int lm = lane & 15, quad = lane >> 4;
    const int qbase = qblk * 128 + wave * 32;

    bf16x8 aq[2][2];
    #pragma unroll
    for (int i = 0; i < 2; ++i)
        #pragma unroll
        for (int ks = 0; ks < 2; ++ks)
            aq[i][ks] = *(const bf16x8*)(q + (size_t)(b * 1024 + qbase + 16 * i + lm) * 1024
                                           + h * 64 + ks * 32 + quad * 8);

    f32x4 O[2][4];
    float mi[2][4], li[2][4];
    #pragma unroll
    for (int i = 0; i < 2; ++i) {
        #pragma unroll
        for (int nt = 0; nt < 4; ++nt) O[i][nt] = (f32x4){0.f, 0.f, 0.f, 0.f};
        #pragma unroll
        for (int r = 0; r < 4; ++r) { mi[i][r] = -1e30f; li[i][r] = 0.f; }
    }

    for (int kt = 0; kt < 1024; kt += 32) {
        bf16x8 bkf[2][2];
        #pragma unroll
        for (int jt = 0; jt < 2; ++jt)
            #pragma unroll
            for (int ks = 0; ks < 2; ++ks)
                bkf[jt][ks] = *(const bf16x8*)(k + (size_t)(b * 1024 + kt + 16 * jt + lm) * 1024
                                                 + h * 64 + ks * 32 + quad * 8);
        f32x4 S[2][2];
        #pragma unroll
        for (int i = 0; i < 2; ++i)
            #pragma unroll
            for (int jt = 0; jt < 2; ++jt) {
                S[i][jt] = (f32x4){0.f, 0.f, 0.f, 0.f};
                S[i][jt] = __builtin_amdgcn_mfma_f32_16x16x32_bf16(aq[i][0], bkf[jt][0], S[i][jt], 0, 0, 0);
                S[i][jt] = __builtin_amdgcn_mfma_f32_16x16x32_bf16(aq[i][1], bkf[jt][1], S[i][jt], 0, 0, 0);
            }

        #pragma unroll
        for (int i = 0; i < 2; ++i) {
            #pragma unroll
            for (int r = 0; r < 4; ++r) {
                float s0 = S[i][0][r] * 0.125f;
                float s1 = S[i][1][r] * 0.125f;
                float mx = fmaxf(s0, s1);
                #pragma unroll
                for (int off = 1; off < 16; off <<= 1) mx = fmaxf(mx, __shfl_xor(mx, off));
                float mnew  = fmaxf(mi[i][r], mx);
                float alpha = __expf(mi[i][r] - mnew);
                float p0 = __expf(s0 - mnew);
                float p1 = __expf(s1 - mnew);
                float rs = p0 + p1;
                #pragma unroll
                for (int off = 1; off < 16; off <<= 1) rs += __shfl_xor(rs, off);
                li[i][r] = li[i][r] * alpha + rs;
                mi[i][r] = mnew;
                #pragma unroll
                for (int nt = 0; nt < 4; ++nt) O[i][nt][r] *= alpha;
                int rl = 16 * i + quad * 4 + r;
                lds_p[wave][rl][lm]      = __float2bfloat16(p0);
                lds_p[wave][rl][16 + lm] = __float2bfloat16(p1);
            }
        }
        __syncthreads();

        bf16x8 ap[2], bvf[4];
        #pragma unroll
        for (int i = 0; i < 2; ++i)
            ap[i] = *(const bf16x8*)(&lds_p[wave][16 * i + lm][quad * 8]);
        #pragma unroll
        for (int nt = 0; nt < 4; ++nt)
            bvf[nt] = *(const bf16x8*)(vt + ((size_t)bh * 64 + 16 * nt + lm) * 1024 + kt + quad * 8);
        #pragma unroll
        for (int i = 0; i < 2; ++i)
            #pragma unroll
            for (int nt = 0; nt < 4; ++nt)
                O[i][nt] = __builtin_amdgcn_mfma_f32_16x16x32_bf16(ap[i], bvf[nt], O[i][nt], 0, 0, 0);
        __syncthreads();
    }

    #pragma unroll
    for (int i = 0; i < 2; ++i) {
        #pragma unroll
        for (int nt = 0; nt < 4; ++nt) {
            #pragma unroll
            for (int r = 0; r < 4; ++r) {
                float o = O[i][nt][r] / li[i][r];
                int qrow = qbase + 16 * i + quad * 4 + r;
                out[(size_t)(b * 1024 + qrow) * 1024 + h * 64 + 16 * nt + lm] = o;
            }
        }
    }
}

// ---------------------------------------------------------------------------
extern "C" void kernel_launch(void* const* d_in, const int* in_sizes, int n_in,
                              void* d_out, int out_size, void* d_ws, size_t ws_size,
                              hipStream_t stream)
{
    const float* emb   = (const float*)d_in[0];
    const float* gamma = (const float*)d_in[1];
    const float* beta  = (const float*)d_in[2];
    const float* Wq    = (const float*)d_in[3];
    const float* bq    = (const float*)d_in[4];
    const float* Wk    = (const float*)d_in[5];
    const float* bk    = (const float*)d_in[6];
    const float* Wv    = (const float*)d_in[7];
    const float* bv    = (const float*)d_in[8];
    float* out = (float*)d_out;

    __hip_bfloat16* ws  = (__hip_bfloat16*)d_ws;
    __hip_bfloat16* x   = ws;                            //  4M elems bf16
    __hip_bfloat16* Wt  = x   + (size_t)4096 * 1024;     //  3M elems
    __hip_bfloat16* qkv = Wt  + (size_t)3 * 1024 * 1024; // 12M elems
    __hip_bfloat16* vt  = qkv + (size_t)3 * 4096 * 1024; //  4M elems (46MB total)

    peln_kernel<<<4096, 256, 0, stream>>>(emb, gamma, beta, x);
    wt_kernel<<<dim3(32, 32, 3), dim3(32, 8), 0, stream>>>(Wq, Wk, Wv, Wt);
    qkv_gemm<<<dim3(32, 24), 256, 0, stream>>>(x, Wt, bq, bk, bv, qkv);
    vt_kernel<<<dim3(32, 2, 64), dim3(32, 8), 0, stream>>>(qkv + (size_t)2 * 4096 * 1024, vt);
    attn_kernel<<<512, 256, 0, stream>>>(qkv, qkv + (size_t)4096 * 1024, vt, out);
}

// Round 4
// 196.011 us; speedup vs baseline: 1.4174x; 1.1184x over previous
//
#include <hip/hip_runtime.h>
#include <hip/hip_bf16.h>
#include <math.h>

typedef __attribute__((ext_vector_type(8))) short bf16x8;
typedef __attribute__((ext_vector_type(4))) float f32x4;

// async global->LDS, 16B per lane. LDS dest = wave-uniform base + lane*16.
static __device__ __forceinline__ void gld16(const void* g, void* l) {
    __builtin_amdgcn_global_load_lds(
        (const __attribute__((address_space(1))) unsigned int*)g,
        (__attribute__((address_space(3))) unsigned int*)l, 16, 0, 0);
}

// ---------------------------------------------------------------------------
// Kernel 1: x = LayerNorm(token_embedding + PE)  -> bf16 [4096,1024]
// ---------------------------------------------------------------------------
__global__ __launch_bounds__(256) void peln_kernel(
    const float* __restrict__ emb,
    const float* __restrict__ gamma,
    const float* __restrict__ beta,
    __hip_bfloat16* __restrict__ x)
{
    const int row = blockIdx.x;        // 0..4095
    const int t   = row & 1023;        // position within sequence
    const int tid = threadIdx.x;

    float4 e = ((const float4*)(emb + (size_t)row * 1024))[tid];
    float v[4] = {e.x, e.y, e.z, e.w};
    float s = 0.f, ss = 0.f;
    #pragma unroll
    for (int kk = 0; kk < 4; ++kk) {
        int c = tid * 4 + kk;
        float ang = (float)t * exp2f(-13.287712379549449f * (float)(c >> 1) * (1.0f / 512.0f));
        float pe  = (c & 1) ? cosf(ang) : sinf(ang);
        v[kk] += pe;
        s  += v[kk];
        ss += v[kk] * v[kk];
    }
    #pragma unroll
    for (int off = 1; off < 64; off <<= 1) {
        s  += __shfl_xor(s, off);
        ss += __shfl_xor(ss, off);
    }
    __shared__ float red_s[4], red_ss[4];
    int wave = tid >> 6, lane = tid & 63;
    if (lane == 0) { red_s[wave] = s; red_ss[wave] = ss; }
    __syncthreads();
    float S  = red_s[0] + red_s[1] + red_s[2] + red_s[3];
    float SS = red_ss[0] + red_ss[1] + red_ss[2] + red_ss[3];
    float mu   = S * (1.0f / 1024.0f);
    float var  = SS * (1.0f / 1024.0f) - mu * mu;
    float rstd = rsqrtf(var + 1e-5f);
    #pragma unroll
    for (int kk = 0; kk < 4; ++kk) {
        int c = tid * 4 + kk;
        float y = (v[kk] - mu) * rstd * gamma[c] + beta[c];
        x[(size_t)row * 1024 + c] = __float2bfloat16(y);
    }
}

// ---------------------------------------------------------------------------
// Kernel 2: transpose+cast Wq/Wk/Wv (f32) -> bf16 Wt[3][1024][1024] (N-major)
// ---------------------------------------------------------------------------
__global__ void wt_kernel(const float* __restrict__ Wq,
                          const float* __restrict__ Wk,
                          const float* __restrict__ Wv,
                          __hip_bfloat16* __restrict__ Wt)
{
    __shared__ __hip_bfloat16 tile[32][33];
    int zz = blockIdx.z;
    const float* src = (zz == 0) ? Wq : (zz == 1) ? Wk : Wv;
    __hip_bfloat16* dst = Wt + (size_t)zz * 1024 * 1024;
    int x0 = blockIdx.x * 32, y0 = blockIdx.y * 32;
    int tx = threadIdx.x, ty = threadIdx.y;   // (32,8)
    #pragma unroll
    for (int kk = 0; kk < 4; ++kk)
        tile[ty + 8 * kk][tx] =
            __float2bfloat16(src[(size_t)(y0 + ty + 8 * kk) * 1024 + x0 + tx]);
    __syncthreads();
    #pragma unroll
    for (int kk = 0; kk < 4; ++kk)
        dst[(size_t)(x0 + ty + 8 * kk) * 1024 + y0 + tx] = tile[tx][ty + 8 * kk];
}

// ---------------------------------------------------------------------------
// Kernel 3: fused QKV GEMM, m97 structure + XCD supertiling.
// 1-D grid 768: xcd=id&7 owns N-band of 3 tiles (384 cols, W-band 768KB in L2),
// sweeps M with j fastest (X panel L2 reuse).
// ---------------------------------------------------------------------------
__global__ __launch_bounds__(256) void qkv_gemm(
    const __hip_bfloat16* __restrict__ X,    // [4096,1024] bf16
    const __hip_bfloat16* __restrict__ Wt,   // [3][1024][1024] bf16 N-major
    const float* __restrict__ bq,
    const float* __restrict__ bk,
    const float* __restrict__ bv,
    __hip_bfloat16* __restrict__ qkv)        // [3][4096][1024] bf16
{
    __shared__ __align__(16) __hip_bfloat16 Abuf[128 * 32];  // 8 KB, [row][k]
    __shared__ __align__(16) __hip_bfloat16 Bbuf[128 * 32];  // 8 KB, [n][k]

    const int id   = blockIdx.x;             // 0..767
    const int xcd  = id & 7;
    const int rest = id >> 3;                // 0..95
    const int j    = rest % 3;
    const int mblk = rest / 3;               // 0..31
    const int m0   = mblk * 128;
    const int n0   = (xcd * 3 + j) * 128;    // 0..2944
    const int t    = n0 >> 10;
    const int nn0  = n0 & 1023;
    const __hip_bfloat16* W = Wt + (size_t)t * 1024 * 1024;

    const int tid  = threadIdx.x;
    const int wave = tid >> 6, lane = tid & 63;
    const int wm = wave & 1, wn = wave >> 1;
    const int lm = lane & 15, quad = lane >> 4;

    const int srow = tid >> 2;
    const int skc  = (tid & 3) * 8;
    const __hip_bfloat16* gA0 = X + (size_t)(m0 + srow) * 1024 + skc;
    const __hip_bfloat16* gA1 = X + (size_t)(m0 + 64 + srow) * 1024 + skc;
    const __hip_bfloat16* gB0 = W + (size_t)(nn0 + srow) * 1024 + skc;
    const __hip_bfloat16* gB1 = W + (size_t)(nn0 + 64 + srow) * 1024 + skc;
    __hip_bfloat16* lA0 = Abuf + wave * 512;
    __hip_bfloat16* lA1 = Abuf + 2048 + wave * 512;
    __hip_bfloat16* lB0 = Bbuf + wave * 512;
    __hip_bfloat16* lB1 = Bbuf + 2048 + wave * 512;

    f32x4 acc[4][4];
    #pragma unroll
    for (int i = 0; i < 4; ++i)
        #pragma unroll
        for (int jj = 0; jj < 4; ++jj)
            acc[i][jj] = (f32x4){0.f, 0.f, 0.f, 0.f};

    for (int k0 = 0; k0 < 1024; k0 += 32) {
        gld16(gA0 + k0, lA0);
        gld16(gA1 + k0, lA1);
        gld16(gB0 + k0, lB0);
        gld16(gB1 + k0, lB1);
        __syncthreads();

        bf16x8 a[4], b[4];
        #pragma unroll
        for (int i = 0; i < 4; ++i)
            a[i] = *(const bf16x8*)(Abuf + (size_t)(wm * 64 + i * 16 + lm) * 32 + quad * 8);
        #pragma unroll
        for (int jj = 0; jj < 4; ++jj)
            b[jj] = *(const bf16x8*)(Bbuf + (size_t)(wn * 64 + jj * 16 + lm) * 32 + quad * 8);
        __syncthreads();

        #pragma unroll
        for (int i = 0; i < 4; ++i)
            #pragma unroll
            for (int jj = 0; jj < 4; ++jj)
                acc[i][jj] = __builtin_amdgcn_mfma_f32_16x16x32_bf16(a[i], b[jj], acc[i][jj], 0, 0, 0);
    }

    const float* bias = (t == 0) ? bq : (t == 1) ? bk : bv;
    __hip_bfloat16* out = qkv + (size_t)t * 4096 * 1024;
    #pragma unroll
    for (int jj = 0; jj < 4; ++jj) {
        int col = nn0 + wn * 64 + jj * 16 + lm;
        float bb = bias[col];
        #pragma unroll
        for (int i = 0; i < 4; ++i) {
            #pragma unroll
            for (int r = 0; r < 4; ++r) {
                int row = m0 + wm * 64 + i * 16 + quad * 4 + r;
                out[(size_t)row * 1024 + col] = __float2bfloat16(acc[i][jj][r] + bb);
            }
        }
    }
}

// ---------------------------------------------------------------------------
// Kernel 4: vt[bh][d][n] = v[(b*1024+n)*1024 + h*64 + d]   (V^T per head)
// ---------------------------------------------------------------------------
__global__ void vt_kernel(const __hip_bfloat16* __restrict__ v,
                          __hip_bfloat16* __restrict__ vt)
{
    __shared__ __hip_bfloat16 tile[32][33];
    int bh = blockIdx.z;
    int b = bh >> 4, h = bh & 15;
    int n0 = blockIdx.x * 32, d0 = blockIdx.y * 32;
    int tx = threadIdx.x, ty = threadIdx.y;  // (32,8)
    #pragma unroll
    for (int kk = 0; kk < 4; ++kk)
        tile[ty + 8 * kk][tx] =
            v[(size_t)(b * 1024 + n0 + ty + 8 * kk) * 1024 + h * 64 + d0 + tx];
    __syncthreads();
    #pragma unroll
    for (int kk = 0; kk < 4; ++kk)
        vt[((size_t)bh * 64 + d0 + ty + 8 * kk) * 1024 + n0 + tx] = tile[tx][ty + 8 * kk];
}

// ---------------------------------------------------------------------------
// Kernel 5: flash attention v2 — max-free softmax (|s|<<88, exact in real
// arithmetic), barrier-free (wave-private LDS P slice + wave-local lgkmcnt
// drain; DS pipe is per-wave in-order), K-tile 64, one li butterfly at end.
// ---------------------------------------------------------------------------
__global__ __launch_bounds__(256) void attn_kernel(
    const __hip_bfloat16* __restrict__ q,    // [4096,1024]
    const __hip_bfloat16* __restrict__ k,    // [4096,1024]
    const __hip_bfloat16* __restrict__ vt,   // [64][64][1024]
    float* __restrict__ out)                 // [4096,1024] f32
{
    // stride 68 bf16 = 136B = 34 banks: 4 quads land 8 banks apart -> writes
    // are 2-way (free) only.
    __shared__ __align__(16) __hip_bfloat16 ldsP[4][32][68];
    const int id   = blockIdx.x;             // 0..511
    const int bh   = (id & 7) * 8 + ((id >> 3) & 7);  // XCD-local K/V
    const int qblk = id >> 6;                // 0..7
    const int b = bh >> 4, h = bh & 15;
    const int wave = threadIdx.x >> 6, lane = threadIdx.x & 63;
    const int lm = lane & 15, quad = lane >> 4;
    const int qbase = qblk * 128 + wave * 32;
    const float CEXP = 0.18033688011112042f;  // (1/8) * log2(e)

    bf16x8 aq[2][2];
    #pragma unroll
    for (int i = 0; i < 2; ++i)
        #pragma unroll
        for (int ks = 0; ks < 2; ++ks)
            aq[i][ks] = *(const bf16x8*)(q + (size_t)(b * 1024 + qbase + 16 * i + lm) * 1024
                                           + h * 64 + ks * 32 + quad * 8);

    f32x4 O[2][4];
    float li[2][4];
    #pragma unroll
    for (int i = 0; i < 2; ++i) {
        #pragma unroll
        for (int nt = 0; nt < 4; ++nt) O[i][nt] = (f32x4){0.f, 0.f, 0.f, 0.f};
        #pragma unroll
        for (int r = 0; r < 4; ++r) li[i][r] = 0.f;
    }

    for (int kt = 0; kt < 1024; kt += 64) {
        // ---- S = Q K^T over a 32q x 64k tile ----
        bf16x8 bkf[4][2];
        #pragma unroll
        for (int jt = 0; jt < 4; ++jt)
            #pragma unroll
            for (int ks = 0; ks < 2; ++ks)
                bkf[jt][ks] = *(const bf16x8*)(k + (size_t)(b * 1024 + kt + 16 * jt + lm) * 1024
                                                 + h * 64 + ks * 32 + quad * 8);
        f32x4 S[2][4];
        #pragma unroll
        for (int i = 0; i < 2; ++i)
            #pragma unroll
            for (int jt = 0; jt < 4; ++jt) {
                S[i][jt] = (f32x4){0.f, 0.f, 0.f, 0.f};
                S[i][jt] = __builtin_amdgcn_mfma_f32_16x16x32_bf16(aq[i][0], bkf[jt][0], S[i][jt], 0, 0, 0);
                S[i][jt] = __builtin_amdgcn_mfma_f32_16x16x32_bf16(aq[i][1], bkf[jt][1], S[i][jt], 0, 0, 0);
            }

        // ---- P = exp(S/8), li partials, P -> wave-private LDS ----
        #pragma unroll
        for (int i = 0; i < 2; ++i)
            #pragma unroll
            for (int jt = 0; jt < 4; ++jt)
                #pragma unroll
                for (int r = 0; r < 4; ++r) {
                    float p = __builtin_amdgcn_exp2f(S[i][jt][r] * CEXP);
                    li[i][r] += p;
                    ldsP[wave][16 * i + quad * 4 + r][jt * 16 + lm] = __float2bfloat16(p);
                }
        // wave-local: drain own DS writes before re-reading (no block barrier)
        asm volatile("s_waitcnt lgkmcnt(0)" ::: "memory");

        // ---- O += P V : P A-frags from LDS, V B-frags from vt ----
        bf16x8 ap[2][2], bvf[4][2];
        #pragma unroll
        for (int i = 0; i < 2; ++i)
            #pragma unroll
            for (int ks = 0; ks < 2; ++ks)
                ap[i][ks] = *(const bf16x8*)(&ldsP[wave][16 * i + lm][ks * 32 + quad * 8]);
        #pragma unroll
        for (int nt = 0; nt < 4; ++nt)
            #pragma unroll
            for (int ks = 0; ks < 2; ++ks)
                bvf[nt][ks] = *(const bf16x8*)(vt + ((size_t)bh * 64 + 16 * nt + lm) * 1024
                                                  + kt + ks * 32 + quad * 8);
        #pragma unroll
        for (int i = 0; i < 2; ++i)
            #pragma unroll
            for (int nt = 0; nt < 4; ++nt) {
                O[i][nt] = __builtin_amdgcn_mfma_f32_16x16x32_bf16(ap[i][0], bvf[nt][0], O[i][nt], 0, 0, 0);
                O[i][nt] = __builtin_amdgcn_mfma_f32_16x16x32_bf16(ap[i][1], bvf[nt][1], O[i][nt], 0, 0, 0);
            }
        // reads complete before next iteration's writes
        asm volatile("s_waitcnt lgkmcnt(0)" ::: "memory");
    }

    // one butterfly: li over the 16 lanes of each quad
    #pragma unroll
    for (int i = 0; i < 2; ++i)
        #pragma unroll
        for (int r = 0; r < 4; ++r) {
            float v = li[i][r];
            #pragma unroll
            for (int off = 1; off < 16; off <<= 1) v += __shfl_xor(v, off);
            li[i][r] = v;
        }

    #pragma unroll
    for (int i = 0; i < 2; ++i) {
        #pragma unroll
        for (int nt = 0; nt < 4; ++nt) {
            #pragma unroll
            for (int r = 0; r < 4; ++r) {
                float o = O[i][nt][r] / li[i][r];
                int qrow = qbase + 16 * i + quad * 4 + r;
                out[(size_t)(b * 1024 + qrow) * 1024 + h * 64 + 16 * nt + lm] = o;
            }
        }
    }
}

// ---------------------------------------------------------------------------
extern "C" void kernel_launch(void* const* d_in, const int* in_sizes, int n_in,
                              void* d_out, int out_size, void* d_ws, size_t ws_size,
                              hipStream_t stream)
{
    const float* emb   = (const float*)d_in[0];
    const float* gamma = (const float*)d_in[1];
    const float* beta  = (const float*)d_in[2];
    const float* Wq    = (const float*)d_in[3];
    const float* bq    = (const float*)d_in[4];
    const float* Wk    = (const float*)d_in[5];
    const float* bk    = (const float*)d_in[6];
    const float* Wv    = (const float*)d_in[7];
    const float* bv    = (const float*)d_in[8];
    float* out = (float*)d_out;

    __hip_bfloat16* ws  = (__hip_bfloat16*)d_ws;
    __hip_bfloat16* x   = ws;                            //  4M elems bf16
    __hip_bfloat16* Wt  = x   + (size_t)4096 * 1024;     //  3M elems
    __hip_bfloat16* qkv = Wt  + (size_t)3 * 1024 * 1024; // 12M elems
    __hip_bfloat16* vt  = qkv + (size_t)3 * 4096 * 1024; //  4M elems (46MB total)

    peln_kernel<<<4096, 256, 0, stream>>>(emb, gamma, beta, x);
    wt_kernel<<<dim3(32, 32, 3), dim3(32, 8), 0, stream>>>(Wq, Wk, Wv, Wt);
    qkv_gemm<<<768, 256, 0, stream>>>(x, Wt, bq, bk, bv, qkv);
    vt_kernel<<<dim3(32, 2, 64), dim3(32, 8), 0, stream>>>(qkv + (size_t)2 * 4096 * 1024, vt);
    attn_kernel<<<512, 256, 0, stream>>>(qkv, qkv + (size_t)4096 * 1024, vt, out);
}

// Round 5
// 193.438 us; speedup vs baseline: 1.4363x; 1.0133x over previous
//
#include <hip/hip_runtime.h>
#include <hip/hip_bf16.h>
#include <math.h>

typedef __attribute__((ext_vector_type(8))) short bf16x8;
typedef __attribute__((ext_vector_type(4))) short bf16x4;
typedef __attribute__((ext_vector_type(4))) float f32x4;

// async global->LDS, 16B per lane. LDS dest = wave-uniform base + lane*16.
static __device__ __forceinline__ void gld16(const void* g, void* l) {
    __builtin_amdgcn_global_load_lds(
        (const __attribute__((address_space(1))) unsigned int*)g,
        (__attribute__((address_space(3))) unsigned int*)l, 16, 0, 0);
}

static __device__ __forceinline__ short f2bf_s(float f) {
    __hip_bfloat16 h = __float2bfloat16(f);
    short s;
    __builtin_memcpy(&s, &h, 2);
    return s;
}

// ---------------------------------------------------------------------------
// Kernel 1: x = LayerNorm(token_embedding + PE)  -> bf16 [4096,1024]
// ---------------------------------------------------------------------------
__global__ __launch_bounds__(256) void peln_kernel(
    const float* __restrict__ emb,
    const float* __restrict__ gamma,
    const float* __restrict__ beta,
    __hip_bfloat16* __restrict__ x)
{
    const int row = blockIdx.x;        // 0..4095
    const int t   = row & 1023;        // position within sequence
    const int tid = threadIdx.x;

    float4 e = ((const float4*)(emb + (size_t)row * 1024))[tid];
    float v[4] = {e.x, e.y, e.z, e.w};
    float s = 0.f, ss = 0.f;
    #pragma unroll
    for (int kk = 0; kk < 4; ++kk) {
        int c = tid * 4 + kk;
        float ang = (float)t * exp2f(-13.287712379549449f * (float)(c >> 1) * (1.0f / 512.0f));
        float pe  = (c & 1) ? cosf(ang) : sinf(ang);
        v[kk] += pe;
        s  += v[kk];
        ss += v[kk] * v[kk];
    }
    #pragma unroll
    for (int off = 1; off < 64; off <<= 1) {
        s  += __shfl_xor(s, off);
        ss += __shfl_xor(ss, off);
    }
    __shared__ float red_s[4], red_ss[4];
    int wave = tid >> 6, lane = tid & 63;
    if (lane == 0) { red_s[wave] = s; red_ss[wave] = ss; }
    __syncthreads();
    float S  = red_s[0] + red_s[1] + red_s[2] + red_s[3];
    float SS = red_ss[0] + red_ss[1] + red_ss[2] + red_ss[3];
    float mu   = S * (1.0f / 1024.0f);
    float var  = SS * (1.0f / 1024.0f) - mu * mu;
    float rstd = rsqrtf(var + 1e-5f);
    #pragma unroll
    for (int kk = 0; kk < 4; ++kk) {
        int c = tid * 4 + kk;
        float y = (v[kk] - mu) * rstd * gamma[c] + beta[c];
        x[(size_t)row * 1024 + c] = __float2bfloat16(y);
    }
}

// ---------------------------------------------------------------------------
// Kernel 2: transpose+cast Wq/Wk/Wv (f32) -> bf16 Wt[3][1024][1024] (N-major)
// ---------------------------------------------------------------------------
__global__ void wt_kernel(const float* __restrict__ Wq,
                          const float* __restrict__ Wk,
                          const float* __restrict__ Wv,
                          __hip_bfloat16* __restrict__ Wt)
{
    __shared__ __hip_bfloat16 tile[32][33];
    int zz = blockIdx.z;
    const float* src = (zz == 0) ? Wq : (zz == 1) ? Wk : Wv;
    __hip_bfloat16* dst = Wt + (size_t)zz * 1024 * 1024;
    int x0 = blockIdx.x * 32, y0 = blockIdx.y * 32;
    int tx = threadIdx.x, ty = threadIdx.y;   // (32,8)
    #pragma unroll
    for (int kk = 0; kk < 4; ++kk)
        tile[ty + 8 * kk][tx] =
            __float2bfloat16(src[(size_t)(y0 + ty + 8 * kk) * 1024 + x0 + tx]);
    __syncthreads();
    #pragma unroll
    for (int kk = 0; kk < 4; ++kk)
        dst[(size_t)(x0 + ty + 8 * kk) * 1024 + y0 + tx] = tile[tx][ty + 8 * kk];
}

// ---------------------------------------------------------------------------
// Kernel 3: fused QKV GEMM, m97 structure + XCD supertiling.
// ---------------------------------------------------------------------------
__global__ __launch_bounds__(256) void qkv_gemm(
    const __hip_bfloat16* __restrict__ X,    // [4096,1024] bf16
    const __hip_bfloat16* __restrict__ Wt,   // [3][1024][1024] bf16 N-major
    const float* __restrict__ bq,
    const float* __restrict__ bk,
    const float* __restrict__ bv,
    __hip_bfloat16* __restrict__ qkv)        // [3][4096][1024] bf16
{
    __shared__ __align__(16) __hip_bfloat16 Abuf[128 * 32];  // 8 KB, [row][k]
    __shared__ __align__(16) __hip_bfloat16 Bbuf[128 * 32];  // 8 KB, [n][k]

    const int id   = blockIdx.x;             // 0..767
    const int xcd  = id & 7;
    const int rest = id >> 3;                // 0..95
    const int j    = rest % 3;
    const int mblk = rest / 3;               // 0..31
    const int m0   = mblk * 128;
    const int n0   = (xcd * 3 + j) * 128;    // 0..2944
    const int t    = n0 >> 10;
    const int nn0  = n0 & 1023;
    const __hip_bfloat16* W = Wt + (size_t)t * 1024 * 1024;

    const int tid  = threadIdx.x;
    const int wave = tid >> 6, lane = tid & 63;
    const int wm = wave & 1, wn = wave >> 1;
    const int lm = lane & 15, quad = lane >> 4;

    const int srow = tid >> 2;
    const int skc  = (tid & 3) * 8;
    const __hip_bfloat16* gA0 = X + (size_t)(m0 + srow) * 1024 + skc;
    const __hip_bfloat16* gA1 = X + (size_t)(m0 + 64 + srow) * 1024 + skc;
    const __hip_bfloat16* gB0 = W + (size_t)(nn0 + srow) * 1024 + skc;
    const __hip_bfloat16* gB1 = W + (size_t)(nn0 + 64 + srow) * 1024 + skc;
    __hip_bfloat16* lA0 = Abuf + wave * 512;
    __hip_bfloat16* lA1 = Abuf + 2048 + wave * 512;
    __hip_bfloat16* lB0 = Bbuf + wave * 512;
    __hip_bfloat16* lB1 = Bbuf + 2048 + wave * 512;

    f32x4 acc[4][4];
    #pragma unroll
    for (int i = 0; i < 4; ++i)
        #pragma unroll
        for (int jj = 0; jj < 4; ++jj)
            acc[i][jj] = (f32x4){0.f, 0.f, 0.f, 0.f};

    for (int k0 = 0; k0 < 1024; k0 += 32) {
        gld16(gA0 + k0, lA0);
        gld16(gA1 + k0, lA1);
        gld16(gB0 + k0, lB0);
        gld16(gB1 + k0, lB1);
        __syncthreads();

        bf16x8 a[4], b[4];
        #pragma unroll
        for (int i = 0; i < 4; ++i)
            a[i] = *(const bf16x8*)(Abuf + (size_t)(wm * 64 + i * 16 + lm) * 32 + quad * 8);
        #pragma unroll
        for (int jj = 0; jj < 4; ++jj)
            b[jj] = *(const bf16x8*)(Bbuf + (size_t)(wn * 64 + jj * 16 + lm) * 32 + quad * 8);
        __syncthreads();

        #pragma unroll
        for (int i = 0; i < 4; ++i)
            #pragma unroll
            for (int jj = 0; jj < 4; ++jj)
                acc[i][jj] = __builtin_amdgcn_mfma_f32_16x16x32_bf16(a[i], b[jj], acc[i][jj], 0, 0, 0);
    }

    const float* bias = (t == 0) ? bq : (t == 1) ? bk : bv;
    __hip_bfloat16* out = qkv + (size_t)t * 4096 * 1024;
    #pragma unroll
    for (int jj = 0; jj < 4; ++jj) {
        int col = nn0 + wn * 64 + jj * 16 + lm;
        float bb = bias[col];
        #pragma unroll
        for (int i = 0; i < 4; ++i) {
            #pragma unroll
            for (int r = 0; r < 4; ++r) {
                int row = m0 + wm * 64 + i * 16 + quad * 4 + r;
                out[(size_t)row * 1024 + col] = __float2bfloat16(acc[i][jj][r] + bb);
            }
        }
    }
}

// ---------------------------------------------------------------------------
// Kernel 4: vt[bh][d][n] = v[(b*1024+n)*1024 + h*64 + d]   (V^T per head)
// ---------------------------------------------------------------------------
__global__ void vt_kernel(const __hip_bfloat16* __restrict__ v,
                          __hip_bfloat16* __restrict__ vt)
{
    __shared__ __hip_bfloat16 tile[32][33];
    int bh = blockIdx.z;
    int b = bh >> 4, h = bh & 15;
    int n0 = blockIdx.x * 32, d0 = blockIdx.y * 32;
    int tx = threadIdx.x, ty = threadIdx.y;  // (32,8)
    #pragma unroll
    for (int kk = 0; kk < 4; ++kk)
        tile[ty + 8 * kk][tx] =
            v[(size_t)(b * 1024 + n0 + ty + 8 * kk) * 1024 + h * 64 + d0 + tx];
    __syncthreads();
    #pragma unroll
    for (int kk = 0; kk < 4; ++kk)
        vt[((size_t)bh * 64 + d0 + ty + 8 * kk) * 1024 + n0 + tx] = tile[tx][ty + 8 * kk];
}

// ---------------------------------------------------------------------------
// Kernel 5: flash attention v3 — transposed MFMA roles (S^T=K·Q^T, O^T=V^T·P^T)
// so P^T exits in lane-layout with 4 consecutive keys/lane: LDS P-writes are
// ds_write_b64, li is per-lane, epilogue stores are float4. Max-free softmax,
// barrier-free (wave-private double-buffered LDS P + single lgkm drain/iter),
// register-double-buffered K frags (prefetch t+1 during tile t).
// ---------------------------------------------------------------------------
__global__ __launch_bounds__(256, 2) void attn_kernel(
    const __hip_bfloat16* __restrict__ q,    // [4096,1024]
    const __hip_bfloat16* __restrict__ k,    // [4096,1024]
    const __hip_bfloat16* __restrict__ vt,   // [64][64][1024]
    float* __restrict__ out)                 // [4096,1024] f32
{
    // stride 72 bf16 = 144 B = 36 banks: balanced for b64 writes / b128 reads
    __shared__ short ldsPT[4][2][32][72];    // 36,864 B
    const int id   = blockIdx.x;             // 0..511
    const int bh   = (id & 7) * 8 + ((id >> 3) & 7);  // XCD-local K/V
    const int qblk = id >> 6;                // 0..7
    const int b = bh >> 4, h = bh & 15;
    const int wave = threadIdx.x >> 6, lane = threadIdx.x & 63;
    const int lm = lane & 15, quad = lane >> 4;
    const int qbase = qblk * 128 + wave * 32;
    const float CEXP = 0.18033688011112042f;  // (1/8) * log2(e)

    // Q as B-operand frags (col n = q = lm, k = d contiguous)
    bf16x8 bq[2][2];
    #pragma unroll
    for (int i = 0; i < 2; ++i)
        #pragma unroll
        for (int ks = 0; ks < 2; ++ks)
            bq[i][ks] = *(const bf16x8*)(q + (size_t)(b * 1024 + qbase + 16 * i + lm) * 1024
                                           + h * 64 + ks * 32 + quad * 8);

    const __hip_bfloat16* kbase = k + (size_t)(b * 1024) * 1024 + h * 64;
    const __hip_bfloat16* vbase = vt + (size_t)bh * 64 * 1024;

    // K as A-operand frags, register double-buffered
    bf16x8 ak[2][4][2];
    #pragma unroll
    for (int jt = 0; jt < 4; ++jt)
        #pragma unroll
        for (int ks = 0; ks < 2; ++ks)
            ak[0][jt][ks] = *(const bf16x8*)(kbase + (size_t)(16 * jt + lm) * 1024
                                                   + ks * 32 + quad * 8);

    f32x4 OT[4][2];        // [nt = d-tile][i = q-tile]
    float li[2] = {0.f, 0.f};
    #pragma unroll
    for (int nt = 0; nt < 4; ++nt)
        #pragma unroll
        for (int i = 0; i < 2; ++i)
            OT[nt][i] = (f32x4){0.f, 0.f, 0.f, 0.f};

    auto body = [&](int kt, int cur, int nxt) {
        // V frags (A-operand for O^T) — issued early, consumed ~500 cyc later
        bf16x8 av[4][2];
        #pragma unroll
        for (int nt = 0; nt < 4; ++nt)
            #pragma unroll
            for (int ks = 0; ks < 2; ++ks)
                av[nt][ks] = *(const bf16x8*)(vbase + (size_t)(16 * nt + lm) * 1024
                                                    + kt + ks * 32 + quad * 8);
        // S^T = K·Q^T  (rows = keys, cols = q)
        f32x4 ST[2][4];   // [i][jt]
        #pragma unroll
        for (int i = 0; i < 2; ++i)
            #pragma unroll
            for (int jt = 0; jt < 4; ++jt) {
                ST[i][jt] = (f32x4){0.f, 0.f, 0.f, 0.f};
                ST[i][jt] = __builtin_amdgcn_mfma_f32_16x16x32_bf16(ak[cur][jt][0], bq[i][0], ST[i][jt], 0, 0, 0);
                ST[i][jt] = __builtin_amdgcn_mfma_f32_16x16x32_bf16(ak[cur][jt][1], bq[i][1], ST[i][jt], 0, 0, 0);
            }
        // prefetch next K tile into the other register buffer
        const int ktn = (kt + 64) & 1023;    // wraps at end; loads discarded
        #pragma unroll
        for (int jt = 0; jt < 4; ++jt)
            #pragma unroll
            for (int ks = 0; ks < 2; ++ks)
                ak[nxt][jt][ks] = *(const bf16x8*)(kbase + (size_t)(ktn + 16 * jt + lm) * 1024
                                                         + ks * 32 + quad * 8);
        // P^T = exp2(S^T*CEXP): 4 consecutive keys per lane -> b64 LDS writes
        #pragma unroll
        for (int i = 0; i < 2; ++i)
            #pragma unroll
            for (int jt = 0; jt < 4; ++jt) {
                bf16x4 pk;
                #pragma unroll
                for (int r = 0; r < 4; ++r) {
                    float p = __builtin_amdgcn_exp2f(ST[i][jt][r] * CEXP);
                    li[i] += p;
                    pk[r] = f2bf_s(p);
                }
                *(bf16x4*)&ldsPT[wave][cur][16 * i + lm][16 * jt + quad * 4] = pk;
            }
        // wave-local drain of own DS writes (no block barrier anywhere)
        asm volatile("s_waitcnt lgkmcnt(0)" ::: "memory");

        // O^T += V^T · P^T
        bf16x8 bp[2][2];
        #pragma unroll
        for (int i = 0; i < 2; ++i)
            #pragma unroll
            for (int ks = 0; ks < 2; ++ks)
                bp[i][ks] = *(const bf16x8*)&ldsPT[wave][cur][16 * i + lm][ks * 32 + quad * 8];
        #pragma unroll
        for (int nt = 0; nt < 4; ++nt)
            #pragma unroll
            for (int i = 0; i < 2; ++i) {
                OT[nt][i] = __builtin_amdgcn_mfma_f32_16x16x32_bf16(av[nt][0], bp[i][0], OT[nt][i], 0, 0, 0);
                OT[nt][i] = __builtin_amdgcn_mfma_f32_16x16x32_bf16(av[nt][1], bp[i][1], OT[nt][i], 0, 0, 0);
            }
    };

    for (int t2 = 0; t2 < 8; ++t2) {
        body(t2 * 128, 0, 1);
        body(t2 * 128 + 64, 1, 0);
    }

    // li: reduce per-lane partials across the 4 quads (same q = lm)
    #pragma unroll
    for (int i = 0; i < 2; ++i) {
        li[i] += __shfl_xor(li[i], 16);
        li[i] += __shfl_xor(li[i], 32);
    }

    #pragma unroll
    for (int i = 0; i < 2; ++i) {
        float inv = 1.0f / li[i];
        int qrow = qbase + 16 * i + lm;
        #pragma unroll
        for (int nt = 0; nt < 4; ++nt) {
            float4 o4 = {OT[nt][i][0] * inv, OT[nt][i][1] * inv,
                         OT[nt][i][2] * inv, OT[nt][i][3] * inv};
            *(float4*)(out + (size_t)(b * 1024 + qrow) * 1024 + h * 64 + 16 * nt + quad * 4) = o4;
        }
    }
}

// ---------------------------------------------------------------------------
extern "C" void kernel_launch(void* const* d_in, const int* in_sizes, int n_in,
                              void* d_out, int out_size, void* d_ws, size_t ws_size,
                              hipStream_t stream)
{
    const float* emb   = (const float*)d_in[0];
    const float* gamma = (const float*)d_in[1];
    const float* beta  = (const float*)d_in[2];
    const float* Wq    = (const float*)d_in[3];
    const float* bq    = (const float*)d_in[4];
    const float* Wk    = (const float*)d_in[5];
    const float* bk    = (const float*)d_in[6];
    const float* Wv    = (const float*)d_in[7];
    const float* bv    = (const float*)d_in[8];
    float* out = (float*)d_out;

    __hip_bfloat16* ws  = (__hip_bfloat16*)d_ws;
    __hip_bfloat16* x   = ws;                            //  4M elems bf16
    __hip_bfloat16* Wt  = x   + (size_t)4096 * 1024;     //  3M elems
    __hip_bfloat16* qkv = Wt  + (size_t)3 * 1024 * 1024; // 12M elems
    __hip_bfloat16* vt  = qkv + (size_t)3 * 4096 * 1024; //  4M elems (46MB total)

    peln_kernel<<<4096, 256, 0, stream>>>(emb, gamma, beta, x);
    wt_kernel<<<dim3(32, 32, 3), dim3(32, 8), 0, stream>>>(Wq, Wk, Wv, Wt);
    qkv_gemm<<<768, 256, 0, stream>>>(x, Wt, bq, bk, bv, qkv);
    vt_kernel<<<dim3(32, 2, 64), dim3(32, 8), 0, stream>>>(qkv + (size_t)2 * 4096 * 1024, vt);
    attn_kernel<<<512, 256, 0, stream>>>(qkv, qkv + (size_t)4096 * 1024, vt, out);
}